// Round 5
// baseline (514.071 us; speedup 1.0000x reference)
//
#include <hip/hip_runtime.h>

// AttentionPooling: N=262144, DIM=256, H=4, HD=64, B=4096 (batch sorted).
// R10 vs R9 (418 us; attn ~130 us invariant across R1/R8/R9 despite occupancy,
//            coalescing, and chain restructures -> all refuted as limiters;
//            remaining shared suspect: the block=segment execution shape:
//            short-lived blocks, serial prologue, data-dependent trip count,
//            barrier+LDS epilogue, 16-32 block-rounds/CU):
//   Fix: segment-decoupled streaming. 2048 blocks x 256 thr; each WAVE owns a
//        static contiguous 32-row slice (8192 waves x 32 = N exact, no tail).
//        No offs, no __syncthreads, no epilogue reduce. Segment boundaries
//        detected inline from sorted batch[]; partial Sacc/se flushed via
//        coalesced global atomicAdd into zeroed sraw/esum (~1.5 flushes/wave).
//        seg_offsets kernel deleted; preps merged into one dispatch
//        (vwt | qw | zero). Inner dot+butterfly kept from R9 (exonerated).

constexpr int DIM = 256;
constexpr int NH  = 4;
constexpr int HD  = 64;
constexpr float SCL  = 0.125f;   // HD^-0.5
constexpr float EPSV = 1e-8f;

// workspace layout (float offsets)
constexpr int WS_QW   = 0;       // 1024 floats: folded query.key_w
constexpr int WS_QB   = 1024;    // 4 floats
constexpr int WS_OFFS = 1088;    // B+1 ints (fallback path only)
constexpr int WS_VWT  = 8192;    // 65536 floats: float4[jj=0..63][t=0..255]
constexpr int WS_SRAW = 73728;   // B*1024 floats raw S; esum (B*4) follows

// ---- merged prep: blocks [0,64) vwt transpose, [64,68) qw fold, [68,..) zero ----
__global__ void prep_all(const float* __restrict__ query,
                         const float* __restrict__ key_w,
                         const float* __restrict__ key_b,
                         const float* __restrict__ value_w,
                         float* __restrict__ ws, int zero_f4){
  const int bid = blockIdx.x, tid = threadIdx.x;
  if (bid < 64){
    // vwt4[jj*256+t] = value_w[t][4jj..4jj+3]
    float4 v = *(const float4*)(value_w + (size_t)tid*DIM + 4*bid);
    ((float4*)(ws + WS_VWT))[bid*256 + tid] = v;
  } else if (bid < 68){
    int t = (bid - 64)*256 + tid;     // 0..1023
    int h = t >> 8, j = t & 255;
    float acc = 0.f;
    #pragma unroll 8
    for (int d = 0; d < HD; ++d)
      acc += query[h*HD+d] * key_w[(size_t)(h*HD+d)*DIM + j];
    ws[WS_QW + t] = acc;
    if (j == 0){
      float bb = 0.f;
      for (int d = 0; d < HD; ++d)
        bb += query[h*HD+d] * key_b[h*HD+d];
      ws[WS_QB + h] = bb;
    }
  } else {
    float4* z = (float4*)(ws + WS_SRAW);
    const int stride = (gridDim.x - 68) * 256;
    for (int i = (bid - 68)*256 + tid; i < zero_f4; i += stride)
      z[i] = make_float4(0.f, 0.f, 0.f, 0.f);
  }
}

// ---- segment offsets (fallback path only) ----
__global__ void seg_offsets(const int* __restrict__ batch32,
                            int* __restrict__ offs, int N, int B){
  int i = blockIdx.x * 256 + threadIdx.x;
  if (i >= N) return;
  const bool is64 = (batch32[N-1] == 0);
  int v  = is64 ? batch32[2*i] : batch32[i];
  int vp = (i == 0) ? -1 : (is64 ? batch32[2*(i-1)] : batch32[i-1]);
  for (int b = vp + 1; b <= v; ++b) offs[b] = i;
  if (i == N-1)
    for (int b = v + 1; b <= B; ++b) offs[b] = N;
}

// ---- main: segment-decoupled streaming; wave = static 32-row slice ----
__global__ __launch_bounds__(256, 4)
void attn_stream(const float* __restrict__ x,
                 const int* __restrict__ batch32,
                 const float* __restrict__ ws,
                 float* __restrict__ sraw,
                 float* __restrict__ esum,
                 int N, int rpw){
  const int tid  = threadIdx.x;
  const int wave = tid >> 6, lane = tid & 63;
  const int gid  = blockIdx.x * 4 + wave;
  const int start = gid * rpw;
  if (start >= N) return;
  const int end = (start + rpw < N) ? (start + rpw) : N;

  const bool is64 = (batch32[N-1] == 0);   // int64: high word of last elem is 0
  const int bstr  = is64 ? 2 : 1;

  // lane-resident qw fragment: cols [4*lane .. 4*lane+3], all 4 heads
  float qwr[NH][4];
  #pragma unroll
  for (int h = 0; h < NH; ++h){
    float4 q = *(const float4*)(ws + WS_QW + h*DIM + 4*lane);
    qwr[h][0]=q.x; qwr[h][1]=q.y; qwr[h][2]=q.z; qwr[h][3]=q.w;
  }
  float qb[NH];
  #pragma unroll
  for (int h = 0; h < NH; ++h) qb[h] = ws[WS_QB + h];

  float Sacc[NH][4];
  #pragma unroll
  for (int h = 0; h < NH; ++h)
    #pragma unroll
    for (int c = 0; c < 4; ++c) Sacc[h][c] = 0.f;
  float se0 = 0.f, se1 = 0.f, se2 = 0.f, se3 = 0.f;

  int cur = batch32[(size_t)start * bstr];

  // flush accumulated segment state via coalesced device-scope atomics
  auto flushfn = [&](int seg){
    #pragma unroll
    for (int h = 0; h < NH; ++h){
      float* bp = sraw + (size_t)seg*1024 + h*256 + 4*lane;
      atomicAdd(bp + 0, Sacc[h][0]);
      atomicAdd(bp + 1, Sacc[h][1]);
      atomicAdd(bp + 2, Sacc[h][2]);
      atomicAdd(bp + 3, Sacc[h][3]);
      Sacc[h][0]=Sacc[h][1]=Sacc[h][2]=Sacc[h][3]=0.f;
    }
    // se values identical across lanes; lanes 0..3 each add one head
    float v = (lane == 0) ? se0 : (lane == 1) ? se1 : (lane == 2) ? se2 : se3;
    if (lane < NH) atomicAdd(esum + seg*4 + lane, v);
    se0 = se1 = se2 = se3 = 0.f;
  };

  const float4* xr4 = (const float4*)x;   // one row = 64 float4

  int n0 = start;
  float4 A[4];
  #pragma unroll
  for (int i = 0; i < 4; ++i){
    int n = n0 + i; n = (n < N-1) ? n : (N-1);
    A[i] = xr4[(size_t)n * 64 + lane];
  }

  while (n0 < end){
    const int nn = n0 + 4;
    // depth-1 prefetch (clamped; always-valid addresses, no divergence)
    float4 An[4];
    #pragma unroll
    for (int i = 0; i < 4; ++i){
      int n = nn + i; n = (n < N-1) ? n : (N-1);
      An[i] = xr4[(size_t)n * 64 + lane];
    }
    // segment ids of this iteration's rows (uniform values, L1-resident)
    int sg[4];
    #pragma unroll
    for (int i = 0; i < 4; ++i)
      sg[i] = batch32[(size_t)(n0 + i) * bstr];

    // per-lane partial dot: p[node][head]
    float p[4][NH];
    #pragma unroll
    for (int i = 0; i < 4; ++i)
      #pragma unroll
      for (int h = 0; h < NH; ++h)
        p[i][h] = qwr[h][0]*A[i].x + qwr[h][1]*A[i].y
                + qwr[h][2]*A[i].z + qwr[h][3]*A[i].w;

    // 16 interleaved butterfly chains, 6 stages
    #pragma unroll
    for (int m = 1; m < 64; m <<= 1){
      #pragma unroll
      for (int i = 0; i < 4; ++i)
        #pragma unroll
        for (int h = 0; h < NH; ++h)
          p[i][h] += __shfl_xor(p[i][h], m, 64);
    }

    // accumulate with boundary flushes (wave-uniform branches)
    #pragma unroll
    for (int i = 0; i < 4; ++i){
      if (sg[i] != cur){ flushfn(cur); cur = sg[i]; }
      const float e0 = __expf((p[i][0] + qb[0]) * SCL);
      const float e1 = __expf((p[i][1] + qb[1]) * SCL);
      const float e2 = __expf((p[i][2] + qb[2]) * SCL);
      const float e3 = __expf((p[i][3] + qb[3]) * SCL);
      se0 += e0; se1 += e1; se2 += e2; se3 += e3;
      Sacc[0][0]+=e0*A[i].x; Sacc[0][1]+=e0*A[i].y; Sacc[0][2]+=e0*A[i].z; Sacc[0][3]+=e0*A[i].w;
      Sacc[1][0]+=e1*A[i].x; Sacc[1][1]+=e1*A[i].y; Sacc[1][2]+=e1*A[i].z; Sacc[1][3]+=e1*A[i].w;
      Sacc[2][0]+=e2*A[i].x; Sacc[2][1]+=e2*A[i].y; Sacc[2][2]+=e2*A[i].z; Sacc[2][3]+=e2*A[i].w;
      Sacc[3][0]+=e3*A[i].x; Sacc[3][1]+=e3*A[i].y; Sacc[3][2]+=e3*A[i].z; Sacc[3][3]+=e3*A[i].w;
    }

    n0 = nn;
    #pragma unroll
    for (int i = 0; i < 4; ++i) A[i] = An[i];
  }
  flushfn(cur);
}

// ---- value projection: TB=8 segments per block, coalesced vwT, reused 8x ----
__global__ __launch_bounds__(256, 4)
void val_proj(const float* __restrict__ ws,
              const float* __restrict__ sraw,
              const float* __restrict__ esum,
              const float* __restrict__ value_b,
              float* __restrict__ out){
  constexpr int TB  = 8;
  constexpr int TBP = 9;                          // +1 pad: kills staging conflict
  __shared__ __align__(16) float Sl[NH*DIM*TBP];  // [rem][i] padded, 36 KB
  const int b0  = blockIdx.x * TB;
  const int tid = threadIdx.x;

  for (int idx = tid; idx < NH*DIM*TB; idx += 256){
    const int i = idx >> 10, rem = idx & 1023;    // rem = h*256+j
    Sl[rem*TBP + i] = sraw[(size_t)(b0 + i)*1024 + rem];
  }
  __syncthreads();

  const int t = tid, h = t >> 6;                  // per-wave-uniform h
  const float4* vwt4 = (const float4*)(ws + WS_VWT);
  float acc[TB];
  #pragma unroll
  for (int i = 0; i < TB; ++i) acc[i] = 0.f;

  #pragma unroll 4
  for (int jj = 0; jj < 64; ++jj){
    const float4 w4 = vwt4[jj*256 + t];           // coalesced, L2-resident
    #pragma unroll
    for (int r = 0; r < 4; ++r){
      const float* sp = &Sl[(h*256 + 4*jj + r)*TBP];  // broadcast reads
      const float wr = (&w4.x)[r];
      acc[0] += wr*sp[0]; acc[1] += wr*sp[1]; acc[2] += wr*sp[2]; acc[3] += wr*sp[3];
      acc[4] += wr*sp[4]; acc[5] += wr*sp[5]; acc[6] += wr*sp[6]; acc[7] += wr*sp[7];
    }
  }
  const float vb = value_b[t];
  #pragma unroll
  for (int i = 0; i < TB; ++i){
    const float es  = esum[(b0 + i)*4 + h];
    const float inv = 1.f / (es + EPSV);
    out[(size_t)(b0 + i)*256 + t] = acc[i]*inv + es*inv*vb;
  }
}

// ---- fused fallback (512 thr/segment) for small workspace ----
template<int MODE>
__global__ __launch_bounds__(512, 4)
void attn_pool_fused(const float* __restrict__ x,
                     const int* __restrict__ offs,
                     const float* __restrict__ ws,
                     const float* __restrict__ value_w,
                     const float* __restrict__ value_b,
                     float* __restrict__ out){
  constexpr int LDSF = (MODE == 1) ? (8192 + 32 + 1024 + 2048 + 8)
                                   : (8192 + 32 + 1024 + 512 + 8);
  __shared__ __align__(16) float lds[LDSF];
  float* S_all    = lds;
  float* sums_all = lds + 8192;

  const int b   = blockIdx.x;
  const int tid = threadIdx.x;
  const int seg_start = offs[b];
  const int seg_end   = offs[b+1];

  const int wave = tid >> 6, lane = tid & 63;
  const int half = lane >> 5, sl = lane & 31;
  const int sigma = wave * 2 + half;

  float qwr[NH][8];
  #pragma unroll
  for (int h = 0; h < NH; ++h){
    float4 a = *(const float4*)(ws + WS_QW + h*DIM + 4*sl);
    float4 c = *(const float4*)(ws + WS_QW + h*DIM + 128 + 4*sl);
    qwr[h][0]=a.x; qwr[h][1]=a.y; qwr[h][2]=a.z; qwr[h][3]=a.w;
    qwr[h][4]=c.x; qwr[h][5]=c.y; qwr[h][6]=c.z; qwr[h][7]=c.w;
  }
  float qb[NH];
  #pragma unroll
  for (int h = 0; h < NH; ++h) qb[h] = ws[WS_QB + h];

  float Sacc[NH][8];
  #pragma unroll
  for (int h = 0; h < NH; ++h)
    #pragma unroll
    for (int c = 0; c < 8; ++c) Sacc[h][c] = 0.f;
  float se[NH] = {0.f, 0.f, 0.f, 0.f};

  const float4* xr4 = (const float4*)x;
  const float4 Z = make_float4(0.f,0.f,0.f,0.f);

  int n0 = seg_start + sigma*2;
  bool v0 = n0 < seg_end;
  bool v1 = n0 + 1 < seg_end;
  float4 a0=Z, b0=Z, a1=Z, b1=Z;
  if (v0){ a0 = xr4[(size_t)n0*64 + sl];     b0 = xr4[(size_t)n0*64 + 32 + sl]; }
  if (v1){ a1 = xr4[(size_t)(n0+1)*64 + sl]; b1 = xr4[(size_t)(n0+1)*64 + 32 + sl]; }

  while (v0){
    const int nn = n0 + 32;
    const bool w0 = nn < seg_end;
    const bool w1 = nn + 1 < seg_end;
    float4 c0=Z, d0=Z, c1=Z, d1=Z;
    if (w0){ c0 = xr4[(size_t)nn*64 + sl];     d0 = xr4[(size_t)nn*64 + 32 + sl]; }
    if (w1){ c1 = xr4[(size_t)(nn+1)*64 + sl]; d1 = xr4[(size_t)(nn+1)*64 + 32 + sl]; }

    float xv0[8] = {a0.x,a0.y,a0.z,a0.w,b0.x,b0.y,b0.z,b0.w};
    float xv1[8] = {a1.x,a1.y,a1.z,a1.w,b1.x,b1.y,b1.z,b1.w};

    float p0[NH], p1[NH];
    #pragma unroll
    for (int h = 0; h < NH; ++h){
      float s0 = 0.f, s1 = 0.f;
      #pragma unroll
      for (int c = 0; c < 8; ++c){ s0 += qwr[h][c]*xv0[c]; s1 += qwr[h][c]*xv1[c]; }
      p0[h] = s0; p1[h] = s1;
    }
    #pragma unroll
    for (int m = 1; m < 32; m <<= 1){
      #pragma unroll
      for (int h = 0; h < NH; ++h){
        p0[h] += __shfl_xor(p0[h], m, 64);
        p1[h] += __shfl_xor(p1[h], m, 64);
      }
    }
    const float g1 = v1 ? 1.f : 0.f;
    #pragma unroll
    for (int h = 0; h < NH; ++h){
      float e0 = __expf((p0[h] + qb[h]) * SCL);
      float e1 = __expf((p1[h] + qb[h]) * SCL) * g1;
      se[h] += e0 + e1;
      #pragma unroll
      for (int c = 0; c < 8; ++c)
        Sacc[h][c] += e0*xv0[c] + e1*xv1[c];
    }
    n0 = nn; v0 = w0; v1 = w1;
    a0 = c0; b0 = d0; a1 = c1; b1 = d1;
  }

  #pragma unroll
  for (int h = 0; h < NH; ++h){
    se[h] += __shfl_xor(se[h], 32, 64);
    #pragma unroll
    for (int c = 0; c < 8; ++c) Sacc[h][c] += __shfl_xor(Sacc[h][c], 32, 64);
  }
  if (half == 0){
    #pragma unroll
    for (int h = 0; h < NH; ++h){
      float4 lo = make_float4(Sacc[h][0], Sacc[h][1], Sacc[h][2], Sacc[h][3]);
      float4 hi = make_float4(Sacc[h][4], Sacc[h][5], Sacc[h][6], Sacc[h][7]);
      *(float4*)&S_all[wave*1024 + h*DIM + 4*sl]       = lo;
      *(float4*)&S_all[wave*1024 + h*DIM + 128 + 4*sl] = hi;
    }
    if (sl == 0){
      #pragma unroll
      for (int h = 0; h < NH; ++h) sums_all[wave*4 + h] = se[h];
    }
  }
  __syncthreads();

  float* Sfin  = lds + 8224;
  float* invs  = (MODE == 1) ? lds + 11296 : lds + 9760;
  float* wsums = invs + 4;
  #pragma unroll
  for (int k = 0; k < 2; ++k){
    const int idx = tid + k*512;
    float sv = 0.f;
    #pragma unroll
    for (int w = 0; w < 8; ++w) sv += S_all[w*1024 + idx];
    Sfin[idx] = sv;
  }
  if (tid < NH){
    float tot = 0.f;
    #pragma unroll
    for (int w = 0; w < 8; ++w) tot += sums_all[w*4 + tid];
    float inv = 1.f / (tot + EPSV);
    invs[tid] = inv; wsums[tid] = tot * inv;
  }
  __syncthreads();

  if constexpr (MODE == 1){
    float* ep = lds + 9248;
    const float4* vwt4 = (const float4*)(ws + WS_VWT);
    const int hh = lane >> 4;
    float4 acc = make_float4(0.f, 0.f, 0.f, 0.f);
    for (int jj = wave*8; jj < wave*8 + 8; ++jj){
      float4 q0 = vwt4[jj*256 + 4*lane + 0];
      float4 q1 = vwt4[jj*256 + 4*lane + 1];
      float4 q2 = vwt4[jj*256 + 4*lane + 2];
      float4 q3 = vwt4[jj*256 + 4*lane + 3];
      float4 sf = *(const float4*)&Sfin[hh*256 + 4*jj];
      acc.x += q0.x*sf.x + q0.y*sf.y + q0.z*sf.z + q0.w*sf.w;
      acc.y += q1.x*sf.x + q1.y*sf.y + q1.z*sf.z + q1.w*sf.w;
      acc.z += q2.x*sf.x + q2.y*sf.y + q2.z*sf.z + q2.w*sf.w;
      acc.w += q3.x*sf.x + q3.y*sf.y + q3.z*sf.z + q3.w*sf.w;
    }
    *(float4*)&ep[wave*256 + 4*lane] = acc;
    __syncthreads();
    if (tid < 256){
      const int t = tid, h2 = t >> 6;
      float sv = 0.f;
      #pragma unroll
      for (int w = 0; w < 8; ++w) sv += ep[w*256 + t];
      out[(size_t)b*256 + t] = sv * invs[h2] + wsums[h2] * value_b[t];
    }
  } else {
    float* ep2 = lds + 9248;
    const int t = tid & 255, part = tid >> 8;
    const int h2 = t >> 6;
    const float4* vrow = (const float4*)(value_w + (size_t)t * DIM) + part*32;
    const float4* sp   = (const float4*)&Sfin[h2*256] + part*32;
    float acc = 0.f;
    #pragma unroll
    for (int q = 0; q < 32; ++q){
      float4 r = vrow[q];
      float4 sv = sp[q];
      acc += r.x*sv.x + r.y*sv.y + r.z*sv.z + r.w*sv.w;
    }
    ep2[part*256 + t] = acc;
    __syncthreads();
    if (part == 0)
      out[(size_t)b * DIM + t] = (ep2[t] + ep2[256 + t]) * invs[h2] + wsums[h2] * value_b[t];
  }
}

extern "C" void kernel_launch(void* const* d_in, const int* in_sizes, int n_in,
                              void* d_out, int out_size, void* d_ws, size_t ws_size,
                              hipStream_t stream){
  const float* x       = (const float*)d_in[0];
  const int*   batch   = (const int*)d_in[1];
  const float* query   = (const float*)d_in[2];
  const float* key_w   = (const float*)d_in[3];
  const float* key_b   = (const float*)d_in[4];
  const float* value_w = (const float*)d_in[5];
  const float* value_b = (const float*)d_in[6];
  float* ws  = (float*)d_ws;
  float* out = (float*)d_out;

  const int N = in_sizes[1];        // 262144
  const int B = out_size / DIM;     // 4096

  float* sraw = ws + WS_SRAW;
  float* esum = ws + WS_SRAW + (size_t)B*1024;

  const size_t need_split = ((size_t)WS_SRAW + (size_t)B*1028) * sizeof(float);
  const size_t need_vwt   = ((size_t)WS_VWT + 65536) * sizeof(float);

  if (ws_size >= need_split){
    const int zero_f4 = B * 257;                 // (B*1024 + B*4)/4
    prep_all<<<68 + 1024, 256, 0, stream>>>(query, key_w, key_b, value_w, ws, zero_f4);
    const int rpw = 32;
    const int nblocks = (N + rpw*4 - 1) / (rpw*4);   // 2048
    attn_stream<<<nblocks, 256, 0, stream>>>(x, batch, ws, sraw, esum, N, rpw);
    val_proj<<<B / 8, 256, 0, stream>>>(ws, sraw, esum, value_b, out);
  } else {
    int* offs = (int*)(ws + WS_OFFS);
    prep_all<<<68, 256, 0, stream>>>(query, key_w, key_b, value_w, ws, 0);
    seg_offsets<<<(N + 255) / 256, 256, 0, stream>>>(batch, offs, N, B);
    if (ws_size >= need_vwt)
      attn_pool_fused<1><<<B, 512, 0, stream>>>(x, offs, ws, value_w, value_b, out);
    else
      attn_pool_fused<2><<<B, 512, 0, stream>>>(x, offs, ws, value_w, value_b, out);
  }
}

// Round 6
// 446.444 us; speedup vs baseline: 1.1515x; 1.1515x over previous
//
#include <hip/hip_runtime.h>

// AttentionPooling: N=262144, DIM=256, H=4, HD=64, B=4096 (batch sorted).
// R11 vs R10 (514 us; atomics cost ~80 us -> reverted. Key insight: fill
//            kernels hit 6.7 TB/s at 5% VALU / 10% occ (writes = no latency),
//            while ALL our read kernels sit at 2.1 TB/s: reads need
//            outstanding-bytes >= BW x latency. R9 kept only ~45 KB/CU in
//            flight (depth-1 prefetch, vmcnt(0) drain per iteration) vs
//            BDP ~30 KB/CU-share at loaded latency -> knee of the curve.
//            Occupancy/coalescing/chain fixes never touched depth -> neutral):
//   Fix: 8-row chunks, full register double-buffer (B0/B1 = 8 x float4 each);
//        next chunk's 8 loads issue BEFORE computing current chunk ->
//        8 KB/wave posted; ~136 VGPR at __launch_bounds__(256,3) ->
//        12 waves/CU x 8 KB = 96 KB/CU in flight (~3x BDP).
//        Wave-uniform gated loads (zero-fill, no waste traffic, no divergence).
//        Consume code = R9's exonerated dot+butterfly. No atomics: per-segment
//        sraw partial + val_proj (R9 padded). Block = segment (exonerated).

constexpr int DIM = 256;
constexpr int NH  = 4;
constexpr int HD  = 64;
constexpr float SCL  = 0.125f;   // HD^-0.5
constexpr float EPSV = 1e-8f;

// workspace layout (float offsets)
constexpr int WS_QW   = 0;       // 1024 floats: folded query.key_w
constexpr int WS_QB   = 1024;    // 4 floats
constexpr int WS_OFFS = 1088;    // B+1 ints
constexpr int WS_VWT  = 8192;    // 65536 floats: float4[jj=0..63][t=0..255]
constexpr int WS_SRAW = 73728;   // B*1024 floats raw S; esum (B*4) follows

// ---- merged prep: blocks [0,64) vwt transpose, [64,68) qw fold ----
__global__ void prep_all(const float* __restrict__ query,
                         const float* __restrict__ key_w,
                         const float* __restrict__ key_b,
                         const float* __restrict__ value_w,
                         float* __restrict__ ws){
  const int bid = blockIdx.x, tid = threadIdx.x;
  if (bid < 64){
    float4 v = *(const float4*)(value_w + (size_t)tid*DIM + 4*bid);
    ((float4*)(ws + WS_VWT))[bid*256 + tid] = v;
  } else {
    int t = (bid - 64)*256 + tid;     // 0..1023
    int h = t >> 8, j = t & 255;
    float acc = 0.f;
    #pragma unroll 8
    for (int d = 0; d < HD; ++d)
      acc += query[h*HD+d] * key_w[(size_t)(h*HD+d)*DIM + j];
    ws[WS_QW + t] = acc;
    if (j == 0){
      float bb = 0.f;
      for (int d = 0; d < HD; ++d)
        bb += query[h*HD+d] * key_b[h*HD+d];
      ws[WS_QB + h] = bb;
    }
  }
}

// ---- segment offsets: offs[b] = first i with batch[i] >= b; offs[B] = N ----
__global__ void seg_offsets(const int* __restrict__ batch32,
                            int* __restrict__ offs, int N, int B){
  int i = blockIdx.x * 256 + threadIdx.x;
  if (i >= N) return;
  const bool is64 = (batch32[N-1] == 0);   // int64 layout: high word of last elem is 0
  int v  = is64 ? batch32[2*i] : batch32[i];
  int vp = (i == 0) ? -1 : (is64 ? batch32[2*(i-1)] : batch32[i-1]);
  for (int b = vp + 1; b <= v; ++b) offs[b] = i;
  if (i == N-1)
    for (int b = v + 1; b <= B; ++b) offs[b] = N;
}

// ---- main: one block (4 waves) per segment; 8-row chunks, reg double-buffer ----
__global__ __launch_bounds__(256, 3)
void attn_chunk(const float* __restrict__ x,
                const int* __restrict__ offs,
                const float* __restrict__ ws,
                float* __restrict__ sraw,
                float* __restrict__ esum){
  __shared__ __align__(16) float S_all[4][NH*DIM];   // 16 KB per-wave partial S
  __shared__ float sums_all[4][NH];

  const int b   = blockIdx.x;
  const int tid = threadIdx.x;
  const int s = offs[b], e = offs[b+1];
  const int wave = tid >> 6, lane = tid & 63;

  // lane-resident qw fragment: cols [4*lane .. 4*lane+3], all 4 heads
  float qwr[NH][4];
  #pragma unroll
  for (int h = 0; h < NH; ++h){
    float4 q = *(const float4*)(ws + WS_QW + h*DIM + 4*lane);
    qwr[h][0]=q.x; qwr[h][1]=q.y; qwr[h][2]=q.z; qwr[h][3]=q.w;
  }
  float qb[NH];
  #pragma unroll
  for (int h = 0; h < NH; ++h) qb[h] = ws[WS_QB + h];

  float Sacc[NH][4];
  #pragma unroll
  for (int h = 0; h < NH; ++h)
    #pragma unroll
    for (int c = 0; c < 4; ++c) Sacc[h][c] = 0.f;
  float se[NH] = {0.f, 0.f, 0.f, 0.f};

  const float4* xr4 = (const float4*)x;   // one row = 64 float4
  const float4 Z = make_float4(0.f, 0.f, 0.f, 0.f);

  // compute one 8-row chunk from a register buffer (two 4-row butterfly batches)
  auto compute8 = [&](const float4* Bv, int base){
    #pragma unroll
    for (int sb = 0; sb < 2; ++sb){
      float p[4][NH];
      #pragma unroll
      for (int i = 0; i < 4; ++i){
        const float4 A = Bv[4*sb + i];
        #pragma unroll
        for (int h = 0; h < NH; ++h)
          p[i][h] = qwr[h][0]*A.x + qwr[h][1]*A.y + qwr[h][2]*A.z + qwr[h][3]*A.w;
      }
      // 16 interleaved butterfly chains, 6 stages
      #pragma unroll
      for (int m = 1; m < 64; m <<= 1){
        #pragma unroll
        for (int i = 0; i < 4; ++i)
          #pragma unroll
          for (int h = 0; h < NH; ++h)
            p[i][h] += __shfl_xor(p[i][h], m, 64);
      }
      #pragma unroll
      for (int i = 0; i < 4; ++i){
        const float4 A = Bv[4*sb + i];
        const bool gv = (base + 4*sb + i) < e;
        #pragma unroll
        for (int h = 0; h < NH; ++h){
          const float ev = gv ? __expf((p[i][h] + qb[h]) * SCL) : 0.f;
          se[h] += ev;
          Sacc[h][0] += ev * A.x;
          Sacc[h][1] += ev * A.y;
          Sacc[h][2] += ev * A.z;
          Sacc[h][3] += ev * A.w;
        }
      }
    }
  };

  // wave handles chunks [s + 8*wave + 32k, +8)
  int n0 = s + wave*8;
  float4 B0[8], B1[8];
  #pragma unroll
  for (int i = 0; i < 8; ++i)
    B0[i] = (n0 + i < e) ? xr4[(size_t)(n0+i)*64 + lane] : Z;   // wave-uniform gate

  while (n0 < e){
    const int nn = n0 + 32;
    #pragma unroll
    for (int i = 0; i < 8; ++i)
      B1[i] = (nn + i < e) ? xr4[(size_t)(nn+i)*64 + lane] : Z;
    compute8(B0, n0);
    n0 = nn;
    if (n0 >= e) break;
    const int nm = n0 + 32;
    #pragma unroll
    for (int i = 0; i < 8; ++i)
      B0[i] = (nm + i < e) ? xr4[(size_t)(nm+i)*64 + lane] : Z;
    compute8(B1, n0);
    n0 = nm;
  }

  // per-wave partial to LDS
  #pragma unroll
  for (int h = 0; h < NH; ++h)
    *(float4*)&S_all[wave][h*DIM + 4*lane] =
        make_float4(Sacc[h][0], Sacc[h][1], Sacc[h][2], Sacc[h][3]);
  if (lane == 0){
    #pragma unroll
    for (int h = 0; h < NH; ++h) sums_all[wave][h] = se[h];
  }
  __syncthreads();

  // reduce 4 wave-copies; 1024 values over 256 threads; store raw S
  #pragma unroll
  for (int k = 0; k < 4; ++k){
    const int idx = tid + k*256;
    const float sv = S_all[0][idx] + S_all[1][idx] + S_all[2][idx] + S_all[3][idx];
    sraw[(size_t)b*1024 + idx] = sv;
  }
  if (tid < NH){
    esum[b*4 + tid] = sums_all[0][tid] + sums_all[1][tid]
                    + sums_all[2][tid] + sums_all[3][tid];
  }
}

// ---- value projection: TB=8 segments per block, coalesced vwT, reused 8x ----
__global__ __launch_bounds__(256, 4)
void val_proj(const float* __restrict__ ws,
              const float* __restrict__ sraw,
              const float* __restrict__ esum,
              const float* __restrict__ value_b,
              float* __restrict__ out){
  constexpr int TB  = 8;
  constexpr int TBP = 9;                          // +1 pad: kills staging conflict
  __shared__ __align__(16) float Sl[NH*DIM*TBP];  // [rem][i] padded, 36 KB
  const int b0  = blockIdx.x * TB;
  const int tid = threadIdx.x;

  for (int idx = tid; idx < NH*DIM*TB; idx += 256){
    const int i = idx >> 10, rem = idx & 1023;    // rem = h*256+j
    Sl[rem*TBP + i] = sraw[(size_t)(b0 + i)*1024 + rem];
  }
  __syncthreads();

  const int t = tid, h = t >> 6;                  // per-wave-uniform h
  const float4* vwt4 = (const float4*)(ws + WS_VWT);
  float acc[TB];
  #pragma unroll
  for (int i = 0; i < TB; ++i) acc[i] = 0.f;

  #pragma unroll 4
  for (int jj = 0; jj < 64; ++jj){
    const float4 w4 = vwt4[jj*256 + t];           // coalesced, L2-resident
    #pragma unroll
    for (int r = 0; r < 4; ++r){
      const float* sp = &Sl[(h*256 + 4*jj + r)*TBP];  // broadcast reads
      const float wr = (&w4.x)[r];
      acc[0] += wr*sp[0]; acc[1] += wr*sp[1]; acc[2] += wr*sp[2]; acc[3] += wr*sp[3];
      acc[4] += wr*sp[4]; acc[5] += wr*sp[5]; acc[6] += wr*sp[6]; acc[7] += wr*sp[7];
    }
  }
  const float vb = value_b[t];
  #pragma unroll
  for (int i = 0; i < TB; ++i){
    const float es  = esum[(b0 + i)*4 + h];
    const float inv = 1.f / (es + EPSV);
    out[(size_t)(b0 + i)*256 + t] = acc[i]*inv + es*inv*vb;
  }
}

// ---- minimal fused fallback (value_w row gather) for tiny workspace ----
__global__ __launch_bounds__(512, 4)
void attn_pool_fused(const float* __restrict__ x,
                     const int* __restrict__ offs,
                     const float* __restrict__ ws,
                     const float* __restrict__ value_w,
                     const float* __restrict__ value_b,
                     float* __restrict__ out){
  __shared__ __align__(16) float lds[8192 + 32 + 1024 + 512 + 8];
  float* S_all    = lds;          // [8][4][256]
  float* sums_all = lds + 8192;   // [8][4]

  const int b   = blockIdx.x;
  const int tid = threadIdx.x;
  const int seg_start = offs[b];
  const int seg_end   = offs[b+1];

  const int wave = tid >> 6, lane = tid & 63;
  const int half = lane >> 5, sl = lane & 31;
  const int sigma = wave * 2 + half;

  float qwr[NH][8];
  #pragma unroll
  for (int h = 0; h < NH; ++h){
    float4 a = *(const float4*)(ws + WS_QW + h*DIM + 4*sl);
    float4 c = *(const float4*)(ws + WS_QW + h*DIM + 128 + 4*sl);
    qwr[h][0]=a.x; qwr[h][1]=a.y; qwr[h][2]=a.z; qwr[h][3]=a.w;
    qwr[h][4]=c.x; qwr[h][5]=c.y; qwr[h][6]=c.z; qwr[h][7]=c.w;
  }
  float qb[NH];
  #pragma unroll
  for (int h = 0; h < NH; ++h) qb[h] = ws[WS_QB + h];

  float Sacc[NH][8];
  #pragma unroll
  for (int h = 0; h < NH; ++h)
    #pragma unroll
    for (int c = 0; c < 8; ++c) Sacc[h][c] = 0.f;
  float se[NH] = {0.f, 0.f, 0.f, 0.f};

  const float4* xr4 = (const float4*)x;
  const float4 Z = make_float4(0.f,0.f,0.f,0.f);

  int n0 = seg_start + sigma*2;
  bool v0 = n0 < seg_end;
  bool v1 = n0 + 1 < seg_end;
  float4 a0=Z, b0=Z, a1=Z, b1=Z;
  if (v0){ a0 = xr4[(size_t)n0*64 + sl];     b0 = xr4[(size_t)n0*64 + 32 + sl]; }
  if (v1){ a1 = xr4[(size_t)(n0+1)*64 + sl]; b1 = xr4[(size_t)(n0+1)*64 + 32 + sl]; }

  while (v0){
    const int nn = n0 + 32;
    const bool w0 = nn < seg_end;
    const bool w1 = nn + 1 < seg_end;
    float4 c0=Z, d0=Z, c1=Z, d1=Z;
    if (w0){ c0 = xr4[(size_t)nn*64 + sl];     d0 = xr4[(size_t)nn*64 + 32 + sl]; }
    if (w1){ c1 = xr4[(size_t)(nn+1)*64 + sl]; d1 = xr4[(size_t)(nn+1)*64 + 32 + sl]; }

    float xv0[8] = {a0.x,a0.y,a0.z,a0.w,b0.x,b0.y,b0.z,b0.w};
    float xv1[8] = {a1.x,a1.y,a1.z,a1.w,b1.x,b1.y,b1.z,b1.w};

    float p0[NH], p1[NH];
    #pragma unroll
    for (int h = 0; h < NH; ++h){
      float s0 = 0.f, s1 = 0.f;
      #pragma unroll
      for (int c = 0; c < 8; ++c){ s0 += qwr[h][c]*xv0[c]; s1 += qwr[h][c]*xv1[c]; }
      p0[h] = s0; p1[h] = s1;
    }
    #pragma unroll
    for (int m = 1; m < 32; m <<= 1){
      #pragma unroll
      for (int h = 0; h < NH; ++h){
        p0[h] += __shfl_xor(p0[h], m, 64);
        p1[h] += __shfl_xor(p1[h], m, 64);
      }
    }
    const float g1 = v1 ? 1.f : 0.f;
    #pragma unroll
    for (int h = 0; h < NH; ++h){
      float e0 = __expf((p0[h] + qb[h]) * SCL);
      float e1 = __expf((p1[h] + qb[h]) * SCL) * g1;
      se[h] += e0 + e1;
      #pragma unroll
      for (int c = 0; c < 8; ++c)
        Sacc[h][c] += e0*xv0[c] + e1*xv1[c];
    }
    n0 = nn; v0 = w0; v1 = w1;
    a0 = c0; b0 = d0; a1 = c1; b1 = d1;
  }

  #pragma unroll
  for (int h = 0; h < NH; ++h){
    se[h] += __shfl_xor(se[h], 32, 64);
    #pragma unroll
    for (int c = 0; c < 8; ++c) Sacc[h][c] += __shfl_xor(Sacc[h][c], 32, 64);
  }
  if (half == 0){
    #pragma unroll
    for (int h = 0; h < NH; ++h){
      float4 lo = make_float4(Sacc[h][0], Sacc[h][1], Sacc[h][2], Sacc[h][3]);
      float4 hi = make_float4(Sacc[h][4], Sacc[h][5], Sacc[h][6], Sacc[h][7]);
      *(float4*)&S_all[wave*1024 + h*DIM + 4*sl]       = lo;
      *(float4*)&S_all[wave*1024 + h*DIM + 128 + 4*sl] = hi;
    }
    if (sl == 0){
      #pragma unroll
      for (int h = 0; h < NH; ++h) sums_all[wave*4 + h] = se[h];
    }
  }
  __syncthreads();

  float* Sfin  = lds + 8224;
  float* invs  = lds + 9760;
  float* wsums = invs + 4;
  #pragma unroll
  for (int k = 0; k < 2; ++k){
    const int idx = tid + k*512;
    float sv = 0.f;
    #pragma unroll
    for (int w = 0; w < 8; ++w) sv += S_all[w*1024 + idx];
    Sfin[idx] = sv;
  }
  if (tid < NH){
    float tot = 0.f;
    #pragma unroll
    for (int w = 0; w < 8; ++w) tot += sums_all[w*4 + tid];
    float inv = 1.f / (tot + EPSV);
    invs[tid] = inv; wsums[tid] = tot * inv;
  }
  __syncthreads();

  float* ep2 = lds + 9248;
  const int t = tid & 255, part = tid >> 8;
  const int h2 = t >> 6;
  const float4* vrow = (const float4*)(value_w + (size_t)t * DIM) + part*32;
  const float4* sp   = (const float4*)&Sfin[h2*256] + part*32;
  float acc = 0.f;
  #pragma unroll
  for (int q = 0; q < 32; ++q){
    float4 r = vrow[q];
    float4 sv = sp[q];
    acc += r.x*sv.x + r.y*sv.y + r.z*sv.z + r.w*sv.w;
  }
  ep2[part*256 + t] = acc;
  __syncthreads();
  if (part == 0)
    out[(size_t)b * DIM + t] = (ep2[t] + ep2[256 + t]) * invs[h2] + wsums[h2] * value_b[t];
}

extern "C" void kernel_launch(void* const* d_in, const int* in_sizes, int n_in,
                              void* d_out, int out_size, void* d_ws, size_t ws_size,
                              hipStream_t stream){
  const float* x       = (const float*)d_in[0];
  const int*   batch   = (const int*)d_in[1];
  const float* query   = (const float*)d_in[2];
  const float* key_w   = (const float*)d_in[3];
  const float* key_b   = (const float*)d_in[4];
  const float* value_w = (const float*)d_in[5];
  const float* value_b = (const float*)d_in[6];
  float* ws  = (float*)d_ws;
  float* out = (float*)d_out;

  const int N = in_sizes[1];        // 262144
  const int B = out_size / DIM;     // 4096

  int*   offs = (int*)(ws + WS_OFFS);
  float* sraw = ws + WS_SRAW;
  float* esum = ws + WS_SRAW + (size_t)B*1024;

  const size_t need_split = ((size_t)WS_SRAW + (size_t)B*1028) * sizeof(float);

  prep_all<<<68, 256, 0, stream>>>(query, key_w, key_b, value_w, ws);
  seg_offsets<<<(N + 255) / 256, 256, 0, stream>>>(batch, offs, N, B);

  if (ws_size >= need_split){
    attn_chunk<<<B, 256, 0, stream>>>(x, offs, ws, sraw, esum);
    val_proj<<<B / 8, 256, 0, stream>>>(ws, sraw, esum, value_b, out);
  } else {
    attn_pool_fused<<<B, 512, 0, stream>>>(x, offs, ws, value_w, value_b, out);
  }
}

// Round 8
// 393.824 us; speedup vs baseline: 1.3053x; 1.1336x over previous
//
#include <hip/hip_runtime.h>

// AttentionPooling: N=262144, DIM=256, H=4, HD=64, B=4096 (batch sorted).
// R13 = R12 with compile fix (__builtin_amdgcn_update_dpp needs a
// constant-expression dpp_ctrl -> template parameter).
//   Budget re-derivation (anchors R2/R10: non-attn = 300 us in both):
//   fill 160 (harness poison) + ~100 us of launch/sync gaps across 5 dispatches
//   + val_proj ~20 + preps ~12. The reducible target is the PLUMBING, not the loop.
//   Fix A: 5 dispatches -> 2. prep+seg merged (disjoint block ranges);
//          val_proj deleted -- value projection fused into attn as the
//          COALESCED vwT epilogue (per-thread dot over L2-resident vwt4,
//          1 KB/instr; not the R0 row-gather). No sraw round-trip at all.
//   Fix B: butterfly 5 DS-stages -> 4 DPP row_ror adds (VALU pipe) +
//          1 ds_swizzle xor16: 8 DS-ops/iter instead of 40.
//   Keep: R8's proven main loop shape (64 VGPR, launch_bounds(256,4), depth-1
//         prefetch, contiguous column loads), single block per segment.

constexpr int DIM = 256;
constexpr int NH  = 4;
constexpr int HD  = 64;
constexpr float SCL  = 0.125f;   // HD^-0.5
constexpr float EPSV = 1e-8f;

// workspace layout (float offsets)
constexpr int WS_QW   = 0;       // 1024 floats: folded query.key_w
constexpr int WS_QB   = 1024;    // 4 floats
constexpr int WS_OFFS = 1088;    // B+1 ints (4097 ints, ends < 8192 floats)
constexpr int WS_VWT  = 8192;    // 65536 floats: float4[jj=0..63][t=0..255]

// ---- DPP/swizzle reduce helpers: sum over a 32-lane group ----
// 4x row_ror (within 16-lane rows, VALU pipe) + 1x ds_swizzle xor16.
template<int CTRL>
__device__ __forceinline__ float dpp_ror_add(float v){
  int r = __builtin_amdgcn_update_dpp(0, __float_as_int(v), CTRL, 0xF, 0xF, false);
  return v + __int_as_float(r);
}
__device__ __forceinline__ float red32(float v){
  v = dpp_ror_add<0x121>(v);   // row_ror:1
  v = dpp_ror_add<0x122>(v);   // row_ror:2
  v = dpp_ror_add<0x124>(v);   // row_ror:4
  v = dpp_ror_add<0x128>(v);   // row_ror:8  -> full 16-lane row sum
  int r = __builtin_amdgcn_ds_swizzle(__float_as_int(v), 0x401F);  // xor16
  return v + __int_as_float(r);
}

// ---- merged prep: [0,64) vwt transpose, [64,68) qw fold, [68,..) seg offsets ----
__global__ void prep_seg(const float* __restrict__ query,
                         const float* __restrict__ key_w,
                         const float* __restrict__ key_b,
                         const float* __restrict__ value_w,
                         const int* __restrict__ batch32,
                         float* __restrict__ ws,
                         int* __restrict__ offs,
                         int N, int B, int do_vwt){
  const int bid = blockIdx.x, tid = threadIdx.x;
  if (bid < 64){
    if (do_vwt){
      float4 v = *(const float4*)(value_w + (size_t)tid*DIM + 4*bid);  // one-time gather
      ((float4*)(ws + WS_VWT))[bid*256 + tid] = v;                     // coalesced write
    }
  } else if (bid < 68){
    int t = (bid - 64)*256 + tid;     // 0..1023
    int h = t >> 8, j = t & 255;
    float acc = 0.f;
    #pragma unroll 8
    for (int d = 0; d < HD; ++d)
      acc += query[h*HD+d] * key_w[(size_t)(h*HD+d)*DIM + j];
    ws[WS_QW + t] = acc;
    if (j == 0){
      float bb = 0.f;
      for (int d = 0; d < HD; ++d)
        bb += query[h*HD+d] * key_b[h*HD+d];
      ws[WS_QB + h] = bb;
    }
  } else {
    int i = (bid - 68)*256 + tid;
    if (i >= N) return;
    const bool is64 = (batch32[N-1] == 0);   // int64: that int is a high word = 0
    int v  = is64 ? batch32[2*i] : batch32[i];
    int vp = (i == 0) ? -1 : (is64 ? batch32[2*(i-1)] : batch32[i-1]);
    for (int b = vp + 1; b <= v; ++b) offs[b] = i;
    if (i == N-1)
      for (int b = v + 1; b <= B; ++b) offs[b] = N;
  }
}

// ---- main: one block (256 thr = 8 half-wave streams) per segment, fused epilogue ----
__global__ __launch_bounds__(256, 4)
void attn_fused2(const float* __restrict__ x,
                 const int* __restrict__ offs,
                 const float* __restrict__ ws,
                 const float* __restrict__ value_b,
                 float* __restrict__ out){
  __shared__ __align__(16) float S_all[4][NH*DIM];   // 16 KB per-wave partial S
  __shared__ __align__(16) float Sfin[NH*DIM];       // 4 KB
  __shared__ float sums_all[4][NH];
  __shared__ float invs[NH], wsums[NH];

  const int b   = blockIdx.x;
  const int tid = threadIdx.x;
  const int s = offs[b], e = offs[b+1];

  const int wave = tid >> 6, lane = tid & 63;
  const int half = lane >> 5, sl = lane & 31;   // half-wave = one stream
  const int sigma = wave * 2 + half;            // stream id 0..7

  // lane-resident qw fragment: cols [4sl..4sl+3] and [128+4sl..128+4sl+3]
  float qwr[NH][8];
  #pragma unroll
  for (int h = 0; h < NH; ++h){
    float4 a = *(const float4*)(ws + WS_QW + h*DIM + 4*sl);
    float4 c = *(const float4*)(ws + WS_QW + h*DIM + 128 + 4*sl);
    qwr[h][0]=a.x; qwr[h][1]=a.y; qwr[h][2]=a.z; qwr[h][3]=a.w;
    qwr[h][4]=c.x; qwr[h][5]=c.y; qwr[h][6]=c.z; qwr[h][7]=c.w;
  }
  float qb[NH];
  #pragma unroll
  for (int h = 0; h < NH; ++h) qb[h] = ws[WS_QB + h];

  float Sacc[NH][8];
  #pragma unroll
  for (int h = 0; h < NH; ++h)
    #pragma unroll
    for (int c = 0; c < 8; ++c) Sacc[h][c] = 0.f;
  float se[NH] = {0.f, 0.f, 0.f, 0.f};

  const float4* xr4 = (const float4*)x;   // one row = 64 float4
  const float4 Z = make_float4(0.f, 0.f, 0.f, 0.f);

  // stream sigma: node pairs (n0, n0+1), n0 = s + 2*sigma + 16k; depth-1 prefetch
  int n0 = s + sigma*2;
  bool v0 = n0 < e;
  bool v1 = n0 + 1 < e;
  float4 a0=Z, b0=Z, a1=Z, b1=Z;
  if (v0){ a0 = xr4[(size_t)n0*64 + sl];     b0 = xr4[(size_t)n0*64 + 32 + sl]; }
  if (v1){ a1 = xr4[(size_t)(n0+1)*64 + sl]; b1 = xr4[(size_t)(n0+1)*64 + 32 + sl]; }

  while (v0){
    const int nn = n0 + 16;
    const bool w0 = nn < e;
    const bool w1 = nn + 1 < e;
    float4 c0=Z, d0=Z, c1=Z, d1=Z;
    if (w0){ c0 = xr4[(size_t)nn*64 + sl];     d0 = xr4[(size_t)nn*64 + 32 + sl]; }
    if (w1){ c1 = xr4[(size_t)(nn+1)*64 + sl]; d1 = xr4[(size_t)(nn+1)*64 + 32 + sl]; }

    float xv0[8] = {a0.x,a0.y,a0.z,a0.w,b0.x,b0.y,b0.z,b0.w};
    float xv1[8] = {a1.x,a1.y,a1.z,a1.w,b1.x,b1.y,b1.z,b1.w};

    float p0[NH], p1[NH];
    #pragma unroll
    for (int h = 0; h < NH; ++h){
      float s0 = 0.f, s1 = 0.f;
      #pragma unroll
      for (int c = 0; c < 8; ++c){ s0 += qwr[h][c]*xv0[c]; s1 += qwr[h][c]*xv1[c]; }
      p0[h] = s0; p1[h] = s1;
    }
    // 8 independent 32-lane reduces: 4 DPP stages (VALU) + 1 ds_swizzle each
    #pragma unroll
    for (int h = 0; h < NH; ++h){
      p0[h] = red32(p0[h]);
      p1[h] = red32(p1[h]);
    }
    const float g1 = v1 ? 1.f : 0.f;
    #pragma unroll
    for (int h = 0; h < NH; ++h){
      float e0 = __expf((p0[h] + qb[h]) * SCL);
      float e1 = __expf((p1[h] + qb[h]) * SCL) * g1;  // xv1 zeroed when !v1
      se[h] += e0 + e1;
      #pragma unroll
      for (int c = 0; c < 8; ++c)
        Sacc[h][c] += e0*xv0[c] + e1*xv1[c];
    }
    n0 = nn; v0 = w0; v1 = w1;
    a0 = c0; b0 = d0; a1 = c1; b1 = d1;
  }

  // combine the two streams of each wave (same columns, different nodes)
  #pragma unroll
  for (int h = 0; h < NH; ++h){
    se[h] += __shfl_xor(se[h], 32, 64);
    #pragma unroll
    for (int c = 0; c < 8; ++c) Sacc[h][c] += __shfl_xor(Sacc[h][c], 32, 64);
  }
  if (half == 0){
    #pragma unroll
    for (int h = 0; h < NH; ++h){
      float4 lo = make_float4(Sacc[h][0], Sacc[h][1], Sacc[h][2], Sacc[h][3]);
      float4 hi = make_float4(Sacc[h][4], Sacc[h][5], Sacc[h][6], Sacc[h][7]);
      *(float4*)&S_all[wave][h*DIM + 4*sl]       = lo;
      *(float4*)&S_all[wave][h*DIM + 128 + 4*sl] = hi;
    }
    if (sl == 0){
      #pragma unroll
      for (int h = 0; h < NH; ++h) sums_all[wave][h] = se[h];
    }
  }
  __syncthreads();

  // reduce 4 wave-copies into Sfin; totals -> invs/wsums
  #pragma unroll
  for (int k = 0; k < 4; ++k){
    const int idx = tid + k*256;
    Sfin[idx] = S_all[0][idx] + S_all[1][idx] + S_all[2][idx] + S_all[3][idx];
  }
  if (tid < NH){
    float tot = sums_all[0][tid] + sums_all[1][tid]
              + sums_all[2][tid] + sums_all[3][tid];
    float inv = 1.f / (tot + EPSV);
    invs[tid]  = inv;
    wsums[tid] = tot * inv;
  }
  __syncthreads();

  // fused COALESCED epilogue: thread t owns out[b,t]; vwt4[jj*256+t] is
  // 1 KB/instr coalesced and L2-resident; Sfin reads are wave-broadcast.
  const int t = tid, h = t >> 6;                  // h wave-uniform
  const float4* vwt4 = (const float4*)(ws + WS_VWT);
  const float4* sp   = (const float4*)&Sfin[h*256];
  float acc = 0.f;
  #pragma unroll 8
  for (int jj = 0; jj < 64; ++jj){
    const float4 w4 = vwt4[jj*256 + t];
    const float4 s4 = sp[jj];
    acc += w4.x*s4.x + w4.y*s4.y + w4.z*s4.z + w4.w*s4.w;
  }
  out[(size_t)b*256 + t] = acc * invs[h] + wsums[h] * value_b[t];
}

// ---- minimal fused fallback (value_w row gather) for tiny workspace ----
__global__ __launch_bounds__(512, 4)
void attn_pool_fused(const float* __restrict__ x,
                     const int* __restrict__ offs,
                     const float* __restrict__ ws,
                     const float* __restrict__ value_w,
                     const float* __restrict__ value_b,
                     float* __restrict__ out){
  __shared__ __align__(16) float lds[8192 + 32 + 1024 + 512 + 8];
  float* S_all    = lds;          // [8][4][256]
  float* sums_all = lds + 8192;   // [8][4]

  const int b   = blockIdx.x;
  const int tid = threadIdx.x;
  const int seg_start = offs[b];
  const int seg_end   = offs[b+1];

  const int wave = tid >> 6, lane = tid & 63;
  const int half = lane >> 5, sl = lane & 31;
  const int sigma = wave * 2 + half;

  float qwr[NH][8];
  #pragma unroll
  for (int h = 0; h < NH; ++h){
    float4 a = *(const float4*)(ws + WS_QW + h*DIM + 4*sl);
    float4 c = *(const float4*)(ws + WS_QW + h*DIM + 128 + 4*sl);
    qwr[h][0]=a.x; qwr[h][1]=a.y; qwr[h][2]=a.z; qwr[h][3]=a.w;
    qwr[h][4]=c.x; qwr[h][5]=c.y; qwr[h][6]=c.z; qwr[h][7]=c.w;
  }
  float qb[NH];
  #pragma unroll
  for (int h = 0; h < NH; ++h) qb[h] = ws[WS_QB + h];

  float Sacc[NH][8];
  #pragma unroll
  for (int h = 0; h < NH; ++h)
    #pragma unroll
    for (int c = 0; c < 8; ++c) Sacc[h][c] = 0.f;
  float se[NH] = {0.f, 0.f, 0.f, 0.f};

  const float4* xr4 = (const float4*)x;
  const float4 Z = make_float4(0.f,0.f,0.f,0.f);

  int n0 = seg_start + sigma*2;
  bool v0 = n0 < seg_end;
  bool v1 = n0 + 1 < seg_end;
  float4 a0=Z, b0=Z, a1=Z, b1=Z;
  if (v0){ a0 = xr4[(size_t)n0*64 + sl];     b0 = xr4[(size_t)n0*64 + 32 + sl]; }
  if (v1){ a1 = xr4[(size_t)(n0+1)*64 + sl]; b1 = xr4[(size_t)(n0+1)*64 + 32 + sl]; }

  while (v0){
    const int nn = n0 + 32;
    const bool w0 = nn < seg_end;
    const bool w1 = nn + 1 < seg_end;
    float4 c0=Z, d0=Z, c1=Z, d1=Z;
    if (w0){ c0 = xr4[(size_t)nn*64 + sl];     d0 = xr4[(size_t)nn*64 + 32 + sl]; }
    if (w1){ c1 = xr4[(size_t)(nn+1)*64 + sl]; d1 = xr4[(size_t)(nn+1)*64 + 32 + sl]; }

    float xv0[8] = {a0.x,a0.y,a0.z,a0.w,b0.x,b0.y,b0.z,b0.w};
    float xv1[8] = {a1.x,a1.y,a1.z,a1.w,b1.x,b1.y,b1.z,b1.w};

    float p0[NH], p1[NH];
    #pragma unroll
    for (int h = 0; h < NH; ++h){
      float s0 = 0.f, s1 = 0.f;
      #pragma unroll
      for (int c = 0; c < 8; ++c){ s0 += qwr[h][c]*xv0[c]; s1 += qwr[h][c]*xv1[c]; }
      p0[h] = s0; p1[h] = s1;
    }
    #pragma unroll
    for (int m = 1; m < 32; m <<= 1){
      #pragma unroll
      for (int h = 0; h < NH; ++h){
        p0[h] += __shfl_xor(p0[h], m, 64);
        p1[h] += __shfl_xor(p1[h], m, 64);
      }
    }
    const float g1 = v1 ? 1.f : 0.f;
    #pragma unroll
    for (int h = 0; h < NH; ++h){
      float e0 = __expf((p0[h] + qb[h]) * SCL);
      float e1 = __expf((p1[h] + qb[h]) * SCL) * g1;
      se[h] += e0 + e1;
      #pragma unroll
      for (int c = 0; c < 8; ++c)
        Sacc[h][c] += e0*xv0[c] + e1*xv1[c];
    }
    n0 = nn; v0 = w0; v1 = w1;
    a0 = c0; b0 = d0; a1 = c1; b1 = d1;
  }

  #pragma unroll
  for (int h = 0; h < NH; ++h){
    se[h] += __shfl_xor(se[h], 32, 64);
    #pragma unroll
    for (int c = 0; c < 8; ++c) Sacc[h][c] += __shfl_xor(Sacc[h][c], 32, 64);
  }
  if (half == 0){
    #pragma unroll
    for (int h = 0; h < NH; ++h){
      float4 lo = make_float4(Sacc[h][0], Sacc[h][1], Sacc[h][2], Sacc[h][3]);
      float4 hi = make_float4(Sacc[h][4], Sacc[h][5], Sacc[h][6], Sacc[h][7]);
      *(float4*)&S_all[wave*1024 + h*DIM + 4*sl]       = lo;
      *(float4*)&S_all[wave*1024 + h*DIM + 128 + 4*sl] = hi;
    }
    if (sl == 0){
      #pragma unroll
      for (int h = 0; h < NH; ++h) sums_all[wave*4 + h] = se[h];
    }
  }
  __syncthreads();

  float* Sfin  = lds + 8224;
  float* invs  = lds + 9760;
  float* wsums = invs + 4;
  #pragma unroll
  for (int k = 0; k < 2; ++k){
    const int idx = tid + k*512;
    float sv = 0.f;
    #pragma unroll
    for (int w = 0; w < 8; ++w) sv += S_all[w*1024 + idx];
    Sfin[idx] = sv;
  }
  if (tid < NH){
    float tot = 0.f;
    #pragma unroll
    for (int w = 0; w < 8; ++w) tot += sums_all[w*4 + tid];
    float inv = 1.f / (tot + EPSV);
    invs[tid] = inv; wsums[tid] = tot * inv;
  }
  __syncthreads();

  float* ep2 = lds + 9248;
  const int t = tid & 255, part = tid >> 8;
  const int h2 = t >> 6;
  const float4* vrow = (const float4*)(value_w + (size_t)t * DIM) + part*32;
  const float4* sp   = (const float4*)&Sfin[h2*256] + part*32;
  float acc = 0.f;
  #pragma unroll
  for (int q = 0; q < 32; ++q){
    float4 r = vrow[q];
    float4 sv = sp[q];
    acc += r.x*sv.x + r.y*sv.y + r.z*sv.z + r.w*sv.w;
  }
  ep2[part*256 + t] = acc;
  __syncthreads();
  if (part == 0)
    out[(size_t)b * DIM + t] = (ep2[t] + ep2[256 + t]) * invs[h2] + wsums[h2] * value_b[t];
}

extern "C" void kernel_launch(void* const* d_in, const int* in_sizes, int n_in,
                              void* d_out, int out_size, void* d_ws, size_t ws_size,
                              hipStream_t stream){
  const float* x       = (const float*)d_in[0];
  const int*   batch   = (const int*)d_in[1];
  const float* query   = (const float*)d_in[2];
  const float* key_w   = (const float*)d_in[3];
  const float* key_b   = (const float*)d_in[4];
  const float* value_w = (const float*)d_in[5];
  const float* value_b = (const float*)d_in[6];
  float* ws  = (float*)d_ws;
  float* out = (float*)d_out;

  const int N = in_sizes[1];        // 262144
  const int B = out_size / DIM;     // 4096

  int* offs = (int*)(ws + WS_OFFS);

  const size_t need_vwt = ((size_t)WS_VWT + 65536) * sizeof(float);
  const int do_vwt = (ws_size >= need_vwt) ? 1 : 0;

  const int seg_blocks = (N + 255) / 256;
  prep_seg<<<68 + seg_blocks, 256, 0, stream>>>(query, key_w, key_b, value_w,
                                                batch, ws, offs, N, B, do_vwt);
  if (do_vwt)
    attn_fused2<<<B, 256, 0, stream>>>(x, offs, ws, value_b, out);
  else
    attn_pool_fused<<<B, 512, 0, stream>>>(x, offs, ws, value_w, value_b, out);
}